// Round 2
// baseline (821.142 us; speedup 1.0000x reference)
//
#include <hip/hip_runtime.h>

#define M_ROWS 8192
#define DIN    4096
#define DOUT   4096
#define RANK   32
#define KAUG   4128   // DIN + RANK
#define ROWS_PB 4     // rows per block in rot_quant

typedef __attribute__((ext_vector_type(8))) short short8;
typedef __attribute__((ext_vector_type(4))) float floatx4;

__device__ __forceinline__ unsigned short f2bf(float f) {
    unsigned int u = __float_as_uint(f);
    unsigned int r = (u + 0x7FFFu + ((u >> 16) & 1u)) >> 16;  // RNE
    return (unsigned short)r;
}

// ---------------------------------------------------------------------------
// Kernel 1 (v2): register-resident FWHT(128) + NVFP4 fake-quant + LoRA T.
// 256 threads handle ROWS_PB=4 rows. Per row: thread t owns the 16 contiguous
// elements [16t, 16t+16) — FWHT stages h=1..8 are in-register, h=16/32/64 are
// __shfl_xor within 8-lane groups (zero LDS, zero barriers for the transform).
// The 16-elem span is exactly one NVFP4 group. x_rot is parked in LDS (bf16)
// so LoRA T amortizes lora_a reads across 4 rows, with 8-lane LDS broadcast.
// ---------------------------------------------------------------------------
__global__ __launch_bounds__(256) void rot_quant_kernel(
    const float* __restrict__ x, const float* __restrict__ sgn,
    const float* __restrict__ lora_a, unsigned short* __restrict__ xaug)
{
    __shared__ unsigned short xrot[ROWS_PB][DIN];   // 32 KiB, bf16 x_rot (scaled)
    __shared__ float tred[ROWS_PB][RANK][8];        // 4 KiB partials

    const int t = threadIdx.x;
    const int row0 = blockIdx.x * ROWS_PB;
    const float inv = 0.08838834764831845f;  // 1/sqrt(128)

    // sign vector: thread's 16 elements, loaded once, held in registers
    float sg[16];
    #pragma unroll
    for (int q = 0; q < 4; ++q)
        *(float4*)&sg[4 * q] = ((const float4*)sgn)[t * 4 + q];

    #pragma unroll 1
    for (int rr = 0; rr < ROWS_PB; ++rr) {
        const float* xr = x + (size_t)(row0 + rr) * DIN;
        float v[16];
        #pragma unroll
        for (int q = 0; q < 4; ++q)
            *(float4*)&v[4 * q] = ((const float4*)xr)[t * 4 + q];
        #pragma unroll
        for (int j = 0; j < 16; ++j) v[j] *= sg[j];

        // FWHT stages h=1,2,4,8: in-register over the 16 contiguous elements
        #pragma unroll
        for (int h = 1; h < 16; h <<= 1) {
            #pragma unroll
            for (int i = 0; i < 16; ++i) {
                if (!(i & h)) {
                    float a = v[i], b = v[i + h];
                    v[i] = a + b;
                    v[i + h] = a - b;
                }
            }
        }
        // FWHT stages h=16,32,64: element index = 16t+j, bit4/5/6 = t&1/t&2/t&4
        #pragma unroll
        for (int m = 1; m <= 4; m <<= 1) {
            const bool up = (t & m) != 0;
            #pragma unroll
            for (int j = 0; j < 16; ++j) {
                float o = __shfl_xor(v[j], m, 64);
                v[j] = up ? (o - v[j]) : (v[j] + o);
            }
        }
        #pragma unroll
        for (int j = 0; j < 16; ++j) v[j] *= inv;

        // park x_rot (bf16) in LDS for the LoRA phase
        {
            unsigned int xp[8];
            #pragma unroll
            for (int j = 0; j < 8; ++j)
                xp[j] = (unsigned int)f2bf(v[2 * j]) |
                        ((unsigned int)f2bf(v[2 * j + 1]) << 16);
            *(uint4*)&xrot[rr][16 * t]     = make_uint4(xp[0], xp[1], xp[2], xp[3]);
            *(uint4*)&xrot[rr][16 * t + 8] = make_uint4(xp[4], xp[5], xp[6], xp[7]);
        }

        // NVFP4 fake-quant of the thread's 16-elem group -> bf16 Xaug
        {
            float amax = 0.f;
            #pragma unroll
            for (int j = 0; j < 16; ++j) amax = fmaxf(amax, fabsf(v[j]));
            amax = fmaxf(amax, 1e-12f);
            float scale = amax / 6.0f;
            unsigned int pk[8];
            #pragma unroll
            for (int j = 0; j < 8; ++j) {
                unsigned short q2[2];
                #pragma unroll
                for (int e = 0; e < 2; ++e) {
                    float vv = v[2 * j + e];
                    float an = fabsf(vv) / scale;
                    float lev = 0.0f;
                    lev = an > 0.25f ? 0.5f : lev;
                    lev = an > 0.75f ? 1.0f : lev;
                    lev = an > 1.25f ? 1.5f : lev;
                    lev = an > 1.75f ? 2.0f : lev;
                    lev = an > 2.5f  ? 3.0f : lev;
                    lev = an > 3.5f  ? 4.0f : lev;
                    lev = an > 5.0f  ? 6.0f : lev;
                    q2[e] = f2bf(copysignf(lev * scale, vv));
                }
                pk[j] = (unsigned int)q2[0] | ((unsigned int)q2[1] << 16);
            }
            unsigned short* orow = xaug + (size_t)(row0 + rr) * KAUG + 16 * t;
            ((uint4*)orow)[0] = make_uint4(pk[0], pk[1], pk[2], pk[3]);
            ((uint4*)orow)[1] = make_uint4(pk[4], pk[5], pk[6], pk[7]);
        }
    }
    __syncthreads();

    // LoRA T[rr][r] = dot(x_rot[rr], lora_a[r]) for 4 rows at once.
    // thread = (r = t>>3, c = t&7): 8 lanes share each LDS read (broadcast),
    // lora_a row r is read by exactly one (r,*) thread-group per block.
    {
        const int r = t >> 3, c = t & 7;
        const float* ar = lora_a + (size_t)r * DIN;
        float acc[ROWS_PB] = {0.f, 0.f, 0.f, 0.f};
        const int d0 = c * 512, d1 = d0 + 512;
        for (int d = d0; d < d1; d += 8) {
            float4 a0 = *(const float4*)(ar + d);
            float4 a1 = *(const float4*)(ar + d + 4);
            #pragma unroll
            for (int rr = 0; rr < ROWS_PB; ++rr) {
                uint4 xb = *(const uint4*)&xrot[rr][d];
                float x0 = __uint_as_float(xb.x << 16);
                float x1 = __uint_as_float(xb.x & 0xFFFF0000u);
                float x2 = __uint_as_float(xb.y << 16);
                float x3 = __uint_as_float(xb.y & 0xFFFF0000u);
                float x4 = __uint_as_float(xb.z << 16);
                float x5 = __uint_as_float(xb.z & 0xFFFF0000u);
                float x6 = __uint_as_float(xb.w << 16);
                float x7 = __uint_as_float(xb.w & 0xFFFF0000u);
                acc[rr] += a0.x * x0 + a0.y * x1 + a0.z * x2 + a0.w * x3 +
                           a1.x * x4 + a1.y * x5 + a1.z * x6 + a1.w * x7;
            }
        }
        #pragma unroll
        for (int rr = 0; rr < ROWS_PB; ++rr) tred[rr][r][c] = acc[rr];
    }
    __syncthreads();
    if (t < ROWS_PB * RANK) {
        const int rr = t >> 5, rk = t & 31;
        float s = 0.f;
        #pragma unroll
        for (int k = 0; k < 8; ++k) s += tred[rr][rk][k];
        xaug[(size_t)(row0 + rr) * KAUG + DIN + rk] = f2bf(s);
    }
}

// ---------------------------------------------------------------------------
// Kernel 2 (v2): vectorized Waug build. float4 loads, uint4 stores.
// ---------------------------------------------------------------------------
__global__ __launch_bounds__(256) void cast_w_kernel(
    const float* __restrict__ w, const float* __restrict__ lora_b,
    unsigned short* __restrict__ waug)
{
    const int n = blockIdx.x;
    const int t = threadIdx.x;
    unsigned short* wr = waug + (size_t)n * KAUG;
    const float* wsrc = w + (size_t)n * DIN;
    #pragma unroll
    for (int it = 0; it < 2; ++it) {
        const int base = (it * 256 + t) * 8;            // 8 elements per step
        float4 a = ((const float4*)wsrc)[base >> 2];
        float4 b = ((const float4*)wsrc)[(base >> 2) + 1];
        unsigned int p0 = (unsigned int)f2bf(a.x) | ((unsigned int)f2bf(a.y) << 16);
        unsigned int p1 = (unsigned int)f2bf(a.z) | ((unsigned int)f2bf(a.w) << 16);
        unsigned int p2 = (unsigned int)f2bf(b.x) | ((unsigned int)f2bf(b.y) << 16);
        unsigned int p3 = (unsigned int)f2bf(b.z) | ((unsigned int)f2bf(b.w) << 16);
        *(uint4*)(wr + base) = make_uint4(p0, p1, p2, p3);
    }
    if (t < RANK)
        wr[DIN + t] = f2bf(lora_b[(size_t)n * RANK + t]);
}

// ---------------------------------------------------------------------------
// Kernel 3: GEMM  C[8192][4096] = Xaug[8192][4128] * Waug[4096][4128]^T + bias
// m97 structure + T1 XCD-aware bijective blockIdx swizzle (nwg=2048, %8==0).
// ---------------------------------------------------------------------------
__global__ __launch_bounds__(256) void gemm_kernel(
    const unsigned short* __restrict__ A,   // [8192][4128] bf16 bits
    const unsigned short* __restrict__ Bm,  // [4096][4128] bf16 bits
    const float* __restrict__ bias,
    float* __restrict__ C)                  // [8192][4096]
{
    __shared__ unsigned short As[128 * 32];
    __shared__ unsigned short Bs[128 * 32];

    // XCD swizzle: blocks with bid%8==x run on XCD x; give each XCD a
    // contiguous chunk of tile-space for L2 locality (2048 % 8 == 0).
    const int cpx = (int)(gridDim.x >> 3);
    const int swz = ((int)blockIdx.x & 7) * cpx + ((int)blockIdx.x >> 3);
    const int nt = swz & 31;                 // 32 n-tiles
    const int mt = swz >> 5;                 // 64 m-tiles
    const int m0 = mt * 128, n0 = nt * 128;
    const int t = threadIdx.x;
    const int wave = t >> 6, lane = t & 63;
    const int wm = wave & 1, wn = wave >> 1; // wave tile 64x64 at (wm,wn)
    const int lm = lane & 15, lq = lane >> 4;

    floatx4 acc[4][4] = {};

    for (int kk = 0; kk < KAUG; kk += 32) {
        __syncthreads();
        // stage: wave w loads chunks 2w, 2w+1 of both tiles (1 KiB each)
        {
            const int c0 = wave * 2;
            const int r_ = (c0 << 4) + (lane >> 2);       // row within tile
            const int colb = (lane & 3) << 3;             // bf16 col offset
            const unsigned short* ga = A + (size_t)(m0 + r_) * KAUG + kk + colb;
            __builtin_amdgcn_global_load_lds(
                (const __attribute__((address_space(1))) void*)ga,
                (__attribute__((address_space(3))) void*)(As + (c0 << 9)), 16, 0, 0);
            __builtin_amdgcn_global_load_lds(
                (const __attribute__((address_space(1))) void*)(ga + (size_t)16 * KAUG),
                (__attribute__((address_space(3))) void*)(As + ((c0 + 1) << 9)), 16, 0, 0);
            const unsigned short* gb = Bm + (size_t)(n0 + r_) * KAUG + kk + colb;
            __builtin_amdgcn_global_load_lds(
                (const __attribute__((address_space(1))) void*)gb,
                (__attribute__((address_space(3))) void*)(Bs + (c0 << 9)), 16, 0, 0);
            __builtin_amdgcn_global_load_lds(
                (const __attribute__((address_space(1))) void*)(gb + (size_t)16 * KAUG),
                (__attribute__((address_space(3))) void*)(Bs + ((c0 + 1) << 9)), 16, 0, 0);
        }
        __syncthreads();

        short8 af[4], bfr[4];
        #pragma unroll
        for (int mi = 0; mi < 4; ++mi)
            af[mi] = *(const short8*)&As[(wm * 64 + mi * 16 + lm) * 32 + lq * 8];
        #pragma unroll
        for (int ni = 0; ni < 4; ++ni)
            bfr[ni] = *(const short8*)&Bs[(wn * 64 + ni * 16 + lm) * 32 + lq * 8];
        #pragma unroll
        for (int mi = 0; mi < 4; ++mi)
            #pragma unroll
            for (int ni = 0; ni < 4; ++ni)
                acc[mi][ni] = __builtin_amdgcn_mfma_f32_16x16x32_bf16(
                    af[mi], bfr[ni], acc[mi][ni], 0, 0, 0);
    }

    // epilogue: += bias, store fp32
    float bv[4];
    #pragma unroll
    for (int ni = 0; ni < 4; ++ni)
        bv[ni] = bias[n0 + wn * 64 + ni * 16 + lm];
    #pragma unroll
    for (int mi = 0; mi < 4; ++mi) {
        #pragma unroll
        for (int ni = 0; ni < 4; ++ni) {
            const int col = n0 + wn * 64 + ni * 16 + lm;
            #pragma unroll
            for (int r = 0; r < 4; ++r) {
                const int rowm = m0 + wm * 64 + mi * 16 + lq * 4 + r;
                C[(size_t)rowm * DOUT + col] = acc[mi][ni][r] + bv[ni];
            }
        }
    }
}

// ---------------------------------------------------------------------------
extern "C" void kernel_launch(void* const* d_in, const int* in_sizes, int n_in,
                              void* d_out, int out_size, void* d_ws, size_t ws_size,
                              hipStream_t stream) {
    const float* x      = (const float*)d_in[0];
    const float* sgn    = (const float*)d_in[1];
    // d_in[2] = H_block (unused; Sylvester Hadamard computed via FWHT)
    const float* w      = (const float*)d_in[3];
    const float* lora_a = (const float*)d_in[4];
    const float* lora_b = (const float*)d_in[5];
    const float* bias   = (const float*)d_in[6];
    float* out = (float*)d_out;

    unsigned short* xaug = (unsigned short*)d_ws;                 // [8192][4128] bf16
    unsigned short* waug = xaug + (size_t)M_ROWS * KAUG;          // [4096][4128] bf16

    rot_quant_kernel<<<M_ROWS / ROWS_PB, 256, 0, stream>>>(x, sgn, lora_a, xaug);
    cast_w_kernel<<<DOUT, 256, 0, stream>>>(w, lora_b, waug);
    gemm_kernel<<<(M_ROWS / 128) * (DOUT / 128), 256, 0, stream>>>(xaug, waug, bias, out);
}

// Round 3
// 688.530 us; speedup vs baseline: 1.1926x; 1.1926x over previous
//
#include <hip/hip_runtime.h>

#define M_ROWS 8192
#define DIN    4096
#define DOUT   4096
#define RANK   32
#define KAUG   4128   // DIN + RANK (valid data)
#define KPAD   4160   // 65*64: K padded to a multiple of BK=64; pad is zeroed
#define KTILES 65
#define ROWS_PB 4     // rows per block in rot_quant

typedef __attribute__((ext_vector_type(8))) short short8;
typedef __attribute__((ext_vector_type(4))) float floatx4;

__device__ __forceinline__ unsigned short f2bf(float f) {
    unsigned int u = __float_as_uint(f);
    unsigned int r = (u + 0x7FFFu + ((u >> 16) & 1u)) >> 16;  // RNE
    return (unsigned short)r;
}

// ---------------------------------------------------------------------------
// Kernel 1: register-resident FWHT(128) + NVFP4 fake-quant + LoRA T.
// 256 threads, ROWS_PB=4 rows/block. FWHT h=1..8 in-register over each
// thread's 16 contiguous elements (== one NVFP4 group), h=16/32/64 via
// __shfl_xor in 8-lane groups. LoRA reads rotated by c*8 elements so the 8
// simultaneous 16B LDS reads hit 8 distinct bank slots (was 8-way conflict).
// ---------------------------------------------------------------------------
__global__ __launch_bounds__(256) void rot_quant_kernel(
    const float* __restrict__ x, const float* __restrict__ sgn,
    const float* __restrict__ lora_a, unsigned short* __restrict__ xaug)
{
    __shared__ unsigned short xrot[ROWS_PB][DIN];   // 32 KiB bf16 x_rot
    __shared__ float tred[ROWS_PB][RANK][8];        // 4 KiB partials

    const int t = threadIdx.x;
    const int row0 = blockIdx.x * ROWS_PB;
    const float inv = 0.08838834764831845f;  // 1/sqrt(128)

    float sg[16];
    #pragma unroll
    for (int q = 0; q < 4; ++q)
        *(float4*)&sg[4 * q] = ((const float4*)sgn)[t * 4 + q];

    // zero the K padding [4128,4160) for this block's rows
    if (t < ROWS_PB * 4) {
        const int rr = t >> 2, q = t & 3;
        *(uint4*)&xaug[(size_t)(row0 + rr) * KPAD + KAUG + q * 8] =
            make_uint4(0, 0, 0, 0);
    }

    #pragma unroll 1
    for (int rr = 0; rr < ROWS_PB; ++rr) {
        const float* xr = x + (size_t)(row0 + rr) * DIN;
        float v[16];
        #pragma unroll
        for (int q = 0; q < 4; ++q)
            *(float4*)&v[4 * q] = ((const float4*)xr)[t * 4 + q];
        #pragma unroll
        for (int j = 0; j < 16; ++j) v[j] *= sg[j];

        // FWHT stages h=1,2,4,8: in-register
        #pragma unroll
        for (int h = 1; h < 16; h <<= 1) {
            #pragma unroll
            for (int i = 0; i < 16; ++i) {
                if (!(i & h)) {
                    float a = v[i], b = v[i + h];
                    v[i] = a + b;
                    v[i + h] = a - b;
                }
            }
        }
        // FWHT stages h=16,32,64: cross-lane within 8-lane groups
        #pragma unroll
        for (int m = 1; m <= 4; m <<= 1) {
            const bool up = (t & m) != 0;
            #pragma unroll
            for (int j = 0; j < 16; ++j) {
                float o = __shfl_xor(v[j], m, 64);
                v[j] = up ? (o - v[j]) : (v[j] + o);
            }
        }
        #pragma unroll
        for (int j = 0; j < 16; ++j) v[j] *= inv;

        // park x_rot (bf16) in LDS for the LoRA phase
        {
            unsigned int xp[8];
            #pragma unroll
            for (int j = 0; j < 8; ++j)
                xp[j] = (unsigned int)f2bf(v[2 * j]) |
                        ((unsigned int)f2bf(v[2 * j + 1]) << 16);
            *(uint4*)&xrot[rr][16 * t]     = make_uint4(xp[0], xp[1], xp[2], xp[3]);
            *(uint4*)&xrot[rr][16 * t + 8] = make_uint4(xp[4], xp[5], xp[6], xp[7]);
        }

        // NVFP4 fake-quant of the 16-elem group -> bf16 Xaug
        {
            float amax = 0.f;
            #pragma unroll
            for (int j = 0; j < 16; ++j) amax = fmaxf(amax, fabsf(v[j]));
            amax = fmaxf(amax, 1e-12f);
            float scale = amax / 6.0f;
            unsigned int pk[8];
            #pragma unroll
            for (int j = 0; j < 8; ++j) {
                unsigned short q2[2];
                #pragma unroll
                for (int e = 0; e < 2; ++e) {
                    float vv = v[2 * j + e];
                    float an = fabsf(vv) / scale;
                    float lev = 0.0f;
                    lev = an > 0.25f ? 0.5f : lev;
                    lev = an > 0.75f ? 1.0f : lev;
                    lev = an > 1.25f ? 1.5f : lev;
                    lev = an > 1.75f ? 2.0f : lev;
                    lev = an > 2.5f  ? 3.0f : lev;
                    lev = an > 3.5f  ? 4.0f : lev;
                    lev = an > 5.0f  ? 6.0f : lev;
                    q2[e] = f2bf(copysignf(lev * scale, vv));
                }
                pk[j] = (unsigned int)q2[0] | ((unsigned int)q2[1] << 16);
            }
            unsigned short* orow = xaug + (size_t)(row0 + rr) * KPAD + 16 * t;
            ((uint4*)orow)[0] = make_uint4(pk[0], pk[1], pk[2], pk[3]);
            ((uint4*)orow)[1] = make_uint4(pk[4], pk[5], pk[6], pk[7]);
        }
    }
    __syncthreads();

    // LoRA T: thread=(r=t>>3, c=t&7); start rotated by c*8 so simultaneous
    // reads cover 8 distinct 16B bank slots (conflict-free).
    {
        const int r = t >> 3, c = t & 7;
        const float* ar = lora_a + (size_t)r * DIN;
        float acc4[ROWS_PB] = {0.f, 0.f, 0.f, 0.f};
        #pragma unroll 1
        for (int i = 0; i < 64; ++i) {
            const int d = (c << 9) + (((i << 3) + (c << 3)) & 511);
            float4 a0 = *(const float4*)(ar + d);
            float4 a1 = *(const float4*)(ar + d + 4);
            #pragma unroll
            for (int rr = 0; rr < ROWS_PB; ++rr) {
                uint4 xb = *(const uint4*)&xrot[rr][d];
                float x0 = __uint_as_float(xb.x << 16);
                float x1 = __uint_as_float(xb.x & 0xFFFF0000u);
                float x2 = __uint_as_float(xb.y << 16);
                float x3 = __uint_as_float(xb.y & 0xFFFF0000u);
                float x4 = __uint_as_float(xb.z << 16);
                float x5 = __uint_as_float(xb.z & 0xFFFF0000u);
                float x6 = __uint_as_float(xb.w << 16);
                float x7 = __uint_as_float(xb.w & 0xFFFF0000u);
                acc4[rr] += a0.x * x0 + a0.y * x1 + a0.z * x2 + a0.w * x3 +
                            a1.x * x4 + a1.y * x5 + a1.z * x6 + a1.w * x7;
            }
        }
        #pragma unroll
        for (int rr = 0; rr < ROWS_PB; ++rr) tred[rr][r][c] = acc4[rr];
    }
    __syncthreads();
    if (t < ROWS_PB * RANK) {
        const int rr = t >> 5, rk = t & 31;
        float s = 0.f;
        #pragma unroll
        for (int k = 0; k < 8; ++k) s += tred[rr][rk][k];
        xaug[(size_t)(row0 + rr) * KPAD + DIN + rk] = f2bf(s);
    }
}

// ---------------------------------------------------------------------------
// Kernel 2: vectorized Waug build (float4 in, uint4 out) + zero K-pad.
// ---------------------------------------------------------------------------
__global__ __launch_bounds__(256) void cast_w_kernel(
    const float* __restrict__ w, const float* __restrict__ lora_b,
    unsigned short* __restrict__ waug)
{
    const int n = blockIdx.x;
    const int t = threadIdx.x;
    unsigned short* wr = waug + (size_t)n * KPAD;
    const float* wsrc = w + (size_t)n * DIN;
    #pragma unroll
    for (int it = 0; it < 2; ++it) {
        const int base = (it * 256 + t) * 8;
        float4 a = ((const float4*)wsrc)[base >> 2];
        float4 b = ((const float4*)wsrc)[(base >> 2) + 1];
        unsigned int p0 = (unsigned int)f2bf(a.x) | ((unsigned int)f2bf(a.y) << 16);
        unsigned int p1 = (unsigned int)f2bf(a.z) | ((unsigned int)f2bf(a.w) << 16);
        unsigned int p2 = (unsigned int)f2bf(b.x) | ((unsigned int)f2bf(b.y) << 16);
        unsigned int p3 = (unsigned int)f2bf(b.z) | ((unsigned int)f2bf(b.w) << 16);
        *(uint4*)(wr + base) = make_uint4(p0, p1, p2, p3);
    }
    if (t < RANK)
        wr[DIN + t] = f2bf(lora_b[(size_t)n * RANK + t]);
    if (t < 4)
        *(uint4*)&wr[KAUG + t * 8] = make_uint4(0, 0, 0, 0);
}

// ---------------------------------------------------------------------------
// Kernel 3: 256x256 8-wave phase-interleaved GEMM (T2+T3+T4+T5).
// C[8192][4096] = Xaug[8192][4160] * Waug[4096][4160]^T + bias.
// BK=64, 4 phases/K-tile x 16 MFMA; next tile staged during current phases;
// counted vmcnt(2) only at P0 (prefetch never drained to 0 mid-loop).
// T2: linear LDS dest + source col-slot XOR (row&7) + same XOR on ds_read.
// No XCD swizzle (measured regression in r2: FETCH +36%, dur +13%).
// ---------------------------------------------------------------------------
__global__ __launch_bounds__(512) void gemm_kernel(
    const unsigned short* __restrict__ A,   // [8192][4160] bf16 bits
    const unsigned short* __restrict__ Bm,  // [4096][4160] bf16 bits
    const float* __restrict__ bias,
    float* __restrict__ C)                  // [8192][4096]
{
    __shared__ unsigned short As[2][256 * 64];   // 64 KiB
    __shared__ unsigned short Bs[2][256 * 64];   // 64 KiB

    const int bid = blockIdx.x;
    const int mt = bid >> 4, nt = bid & 15;      // 32 x 16 tiles
    const int m0 = mt * 256, n0 = nt * 256;
    const int t = threadIdx.x;
    const int wave = t >> 6, lane = t & 63;
    const int wm = wave >> 2, wn = wave & 3;     // wave tile 128x64
    const int lm = lane & 15, lq = lane >> 4;

    // staging geometry: chunk = 8 rows x 64 cols (1 KiB). Lane: row sr,
    // source col-slot pre-swizzled by sr so linear LDS ends up swizzled.
    const int sr = lane >> 3;
    const int ss = (lane & 7) ^ sr;
    const int ca = wave * 4;                     // this wave's 4 chunks

#define STAGE_A(buf, kt, c) do {                                              \
    const unsigned short* g_ = A + (size_t)(m0 + (c) * 8 + sr) * KPAD         \
                                 + (kt) * 64 + ss * 8;                        \
    __builtin_amdgcn_global_load_lds(                                         \
        (const __attribute__((address_space(1))) void*)g_,                    \
        (__attribute__((address_space(3))) void*)(&As[buf][(c) * 512]),       \
        16, 0, 0); } while (0)
#define STAGE_B(buf, kt, c) do {                                              \
    const unsigned short* g_ = Bm + (size_t)(n0 + (c) * 8 + sr) * KPAD        \
                                 + (kt) * 64 + ss * 8;                        \
    __builtin_amdgcn_global_load_lds(                                         \
        (const __attribute__((address_space(1))) void*)g_,                    \
        (__attribute__((address_space(3))) void*)(&Bs[buf][(c) * 512]),       \
        16, 0, 0); } while (0)

    // read-side swizzled byte col offsets (kh=0,1); row byte bases
    const int cb0 = (lq * 16) ^ ((lm & 7) << 4);
    const int cb1 = (64 + lq * 16) ^ ((lm & 7) << 4);
    const int arow = (wm * 128 + lm) * 128;
    const int brow = (wn * 64 + lm) * 128;

    floatx4 acc[8][4] = {};

    // prologue: stage K-tile 0 into buffer 0 (8 loads/thread in flight)
    STAGE_A(0, 0, ca + 0); STAGE_A(0, 0, ca + 1);
    STAGE_A(0, 0, ca + 2); STAGE_A(0, 0, ca + 3);
    STAGE_B(0, 0, ca + 0); STAGE_B(0, 0, ca + 1);
    STAGE_B(0, 0, ca + 2); STAGE_B(0, 0, ca + 3);

    for (int kt = 0; kt < KTILES; ++kt) {
        const int b = kt & 1;
        const char* as = (const char*)&As[b][0];
        const char* bs = (const char*)&Bs[b][0];
        short8 af[4], bf[4];

        // ---- P0: kh0, mi 0..3 (stage next A pair; counted wait; barrier)
        if (kt + 1 < KTILES) {
            STAGE_A(b ^ 1, kt + 1, ca + 0);
            STAGE_A(b ^ 1, kt + 1, ca + 1);
            asm volatile("s_waitcnt vmcnt(2)" ::: "memory");
        } else {
            asm volatile("s_waitcnt vmcnt(0)" ::: "memory");
        }
        __builtin_amdgcn_s_barrier();
        #pragma unroll
        for (int i = 0; i < 4; ++i)
            af[i] = *(const short8*)(as + arow + i * 2048 + cb0);
        #pragma unroll
        for (int j = 0; j < 4; ++j)
            bf[j] = *(const short8*)(bs + brow + j * 2048 + cb0);
        __builtin_amdgcn_s_setprio(1);
        #pragma unroll
        for (int i = 0; i < 4; ++i)
            #pragma unroll
            for (int j = 0; j < 4; ++j)
                acc[i][j] = __builtin_amdgcn_mfma_f32_16x16x32_bf16(
                    af[i], bf[j], acc[i][j], 0, 0, 0);
        __builtin_amdgcn_s_setprio(0);
        __builtin_amdgcn_s_barrier();

        // ---- P1: kh0, mi 4..7 (reuse bf)
        #pragma unroll
        for (int i = 0; i < 4; ++i)
            af[i] = *(const short8*)(as + arow + (i + 4) * 2048 + cb0);
        if (kt + 1 < KTILES) {
            STAGE_A(b ^ 1, kt + 1, ca + 2);
            STAGE_A(b ^ 1, kt + 1, ca + 3);
        }
        __builtin_amdgcn_s_barrier();
        __builtin_amdgcn_s_setprio(1);
        #pragma unroll
        for (int i = 0; i < 4; ++i)
            #pragma unroll
            for (int j = 0; j < 4; ++j)
                acc[i + 4][j] = __builtin_amdgcn_mfma_f32_16x16x32_bf16(
                    af[i], bf[j], acc[i + 4][j], 0, 0, 0);
        __builtin_amdgcn_s_setprio(0);
        __builtin_amdgcn_s_barrier();

        // ---- P2: kh1, mi 0..3 (new bf)
        #pragma unroll
        for (int i = 0; i < 4; ++i)
            af[i] = *(const short8*)(as + arow + i * 2048 + cb1);
        #pragma unroll
        for (int j = 0; j < 4; ++j)
            bf[j] = *(const short8*)(bs + brow + j * 2048 + cb1);
        if (kt + 1 < KTILES) {
            STAGE_B(b ^ 1, kt + 1, ca + 0);
            STAGE_B(b ^ 1, kt + 1, ca + 1);
        }
        __builtin_amdgcn_s_barrier();
        __builtin_amdgcn_s_setprio(1);
        #pragma unroll
        for (int i = 0; i < 4; ++i)
            #pragma unroll
            for (int j = 0; j < 4; ++j)
                acc[i][j] = __builtin_amdgcn_mfma_f32_16x16x32_bf16(
                    af[i], bf[j], acc[i][j], 0, 0, 0);
        __builtin_amdgcn_s_setprio(0);
        __builtin_amdgcn_s_barrier();

        // ---- P3: kh1, mi 4..7
        #pragma unroll
        for (int i = 0; i < 4; ++i)
            af[i] = *(const short8*)(as + arow + (i + 4) * 2048 + cb1);
        if (kt + 1 < KTILES) {
            STAGE_B(b ^ 1, kt + 1, ca + 2);
            STAGE_B(b ^ 1, kt + 1, ca + 3);
        }
        __builtin_amdgcn_s_barrier();
        __builtin_amdgcn_s_setprio(1);
        #pragma unroll
        for (int i = 0; i < 4; ++i)
            #pragma unroll
            for (int j = 0; j < 4; ++j)
                acc[i + 4][j] = __builtin_amdgcn_mfma_f32_16x16x32_bf16(
                    af[i], bf[j], acc[i + 4][j], 0, 0, 0);
        __builtin_amdgcn_s_setprio(0);
        __builtin_amdgcn_s_barrier();
    }

    // epilogue: += bias, store fp32
    float bv[4];
    #pragma unroll
    for (int j = 0; j < 4; ++j)
        bv[j] = bias[n0 + wn * 64 + j * 16 + lm];
    #pragma unroll
    for (int i = 0; i < 8; ++i) {
        #pragma unroll
        for (int j = 0; j < 4; ++j) {
            const int col = n0 + wn * 64 + j * 16 + lm;
            #pragma unroll
            for (int r = 0; r < 4; ++r) {
                const int row = m0 + wm * 128 + i * 16 + lq * 4 + r;
                C[(size_t)row * DOUT + col] = acc[i][j][r] + bv[j];
            }
        }
    }
#undef STAGE_A
#undef STAGE_B
}

// ---------------------------------------------------------------------------
extern "C" void kernel_launch(void* const* d_in, const int* in_sizes, int n_in,
                              void* d_out, int out_size, void* d_ws, size_t ws_size,
                              hipStream_t stream) {
    const float* x      = (const float*)d_in[0];
    const float* sgn    = (const float*)d_in[1];
    // d_in[2] = H_block (unused; Sylvester Hadamard computed via FWHT)
    const float* w      = (const float*)d_in[3];
    const float* lora_a = (const float*)d_in[4];
    const float* lora_b = (const float*)d_in[5];
    const float* bias   = (const float*)d_in[6];
    float* out = (float*)d_out;

    unsigned short* xaug = (unsigned short*)d_ws;                 // [8192][4160] bf16
    unsigned short* waug = xaug + (size_t)M_ROWS * KPAD;          // [4096][4160] bf16

    rot_quant_kernel<<<M_ROWS / ROWS_PB, 256, 0, stream>>>(x, sgn, lora_a, xaug);
    cast_w_kernel<<<DOUT, 256, 0, stream>>>(w, lora_b, waug);
    gemm_kernel<<<(M_ROWS / 256) * (DOUT / 256), 512, 0, stream>>>(xaug, waug, bias, out);
}

// Round 4
// 650.336 us; speedup vs baseline: 1.2626x; 1.0587x over previous
//
#include <hip/hip_runtime.h>

#define M_ROWS 8192
#define DIN    4096
#define DOUT   4096
#define RANK   32
#define KAUG   4128   // DIN + RANK (valid data)
#define KPAD   4160   // 65*64: K padded to multiple of BK=64; pad zeroed
#define KTILES 65
#define ROWS_PB 4     // rows per block in rot_quant role
#define NROTB  (M_ROWS / ROWS_PB)   // 2048 rot blocks

typedef __attribute__((ext_vector_type(8))) short short8;
typedef __attribute__((ext_vector_type(4))) float floatx4;

__device__ __forceinline__ unsigned short f2bf(float f) {
    unsigned int u = __float_as_uint(f);
    unsigned int r = (u + 0x7FFFu + ((u >> 16) & 1u)) >> 16;  // RNE
    return (unsigned short)r;
}

// ---------------------------------------------------------------------------
// Kernel 1 (fused prep): blocks [0,2048) = rot_quant role (4 rows each),
// blocks [2048,6144) = cast_w role. Block-uniform branch; one launch fewer
// and tail overlap between the two independent memory-bound stages.
// ---------------------------------------------------------------------------
__global__ __launch_bounds__(256) void prep_kernel(
    const float* __restrict__ x, const float* __restrict__ sgn,
    const float* __restrict__ lora_a,
    const float* __restrict__ w, const float* __restrict__ lora_b,
    unsigned short* __restrict__ xaug, unsigned short* __restrict__ waug)
{
    __shared__ unsigned short xrot[ROWS_PB][DIN];   // 32 KiB bf16 x_rot
    __shared__ float tred[ROWS_PB][RANK][8];        // 4 KiB partials

    const int t = threadIdx.x;

    if (blockIdx.x >= NROTB) {
        // ---- cast_w role ----
        const int n = blockIdx.x - NROTB;
        unsigned short* wr = waug + (size_t)n * KPAD;
        const float* wsrc = w + (size_t)n * DIN;
        #pragma unroll
        for (int it = 0; it < 2; ++it) {
            const int base = (it * 256 + t) * 8;
            float4 a = ((const float4*)wsrc)[base >> 2];
            float4 b = ((const float4*)wsrc)[(base >> 2) + 1];
            unsigned int p0 = (unsigned int)f2bf(a.x) | ((unsigned int)f2bf(a.y) << 16);
            unsigned int p1 = (unsigned int)f2bf(a.z) | ((unsigned int)f2bf(a.w) << 16);
            unsigned int p2 = (unsigned int)f2bf(b.x) | ((unsigned int)f2bf(b.y) << 16);
            unsigned int p3 = (unsigned int)f2bf(b.z) | ((unsigned int)f2bf(b.w) << 16);
            *(uint4*)(wr + base) = make_uint4(p0, p1, p2, p3);
        }
        if (t < RANK)
            wr[DIN + t] = f2bf(lora_b[(size_t)n * RANK + t]);
        if (t < 4)
            *(uint4*)&wr[KAUG + t * 8] = make_uint4(0, 0, 0, 0);
        return;
    }

    // ---- rot_quant role ----
    const int row0 = blockIdx.x * ROWS_PB;
    const float inv = 0.08838834764831845f;  // 1/sqrt(128)

    float sg[16];
    #pragma unroll
    for (int q = 0; q < 4; ++q)
        *(float4*)&sg[4 * q] = ((const float4*)sgn)[t * 4 + q];

    // zero the K padding [4128,4160)
    if (t < ROWS_PB * 4) {
        const int rr = t >> 2, q = t & 3;
        *(uint4*)&xaug[(size_t)(row0 + rr) * KPAD + KAUG + q * 8] =
            make_uint4(0, 0, 0, 0);
    }

    #pragma unroll 1
    for (int rr = 0; rr < ROWS_PB; ++rr) {
        const float* xr = x + (size_t)(row0 + rr) * DIN;
        float v[16];
        #pragma unroll
        for (int q = 0; q < 4; ++q)
            *(float4*)&v[4 * q] = ((const float4*)xr)[t * 4 + q];
        #pragma unroll
        for (int j = 0; j < 16; ++j) v[j] *= sg[j];

        // FWHT h=1,2,4,8 in-register
        #pragma unroll
        for (int h = 1; h < 16; h <<= 1) {
            #pragma unroll
            for (int i = 0; i < 16; ++i) {
                if (!(i & h)) {
                    float a = v[i], b = v[i + h];
                    v[i] = a + b;
                    v[i + h] = a - b;
                }
            }
        }
        // FWHT h=16,32,64 via shfl_xor in 8-lane groups
        #pragma unroll
        for (int m = 1; m <= 4; m <<= 1) {
            const bool up = (t & m) != 0;
            #pragma unroll
            for (int j = 0; j < 16; ++j) {
                float o = __shfl_xor(v[j], m, 64);
                v[j] = up ? (o - v[j]) : (v[j] + o);
            }
        }
        #pragma unroll
        for (int j = 0; j < 16; ++j) v[j] *= inv;

        // park x_rot bf16 in LDS
        {
            unsigned int xp[8];
            #pragma unroll
            for (int j = 0; j < 8; ++j)
                xp[j] = (unsigned int)f2bf(v[2 * j]) |
                        ((unsigned int)f2bf(v[2 * j + 1]) << 16);
            *(uint4*)&xrot[rr][16 * t]     = make_uint4(xp[0], xp[1], xp[2], xp[3]);
            *(uint4*)&xrot[rr][16 * t + 8] = make_uint4(xp[4], xp[5], xp[6], xp[7]);
        }

        // NVFP4 fake-quant -> bf16 Xaug
        {
            float amax = 0.f;
            #pragma unroll
            for (int j = 0; j < 16; ++j) amax = fmaxf(amax, fabsf(v[j]));
            amax = fmaxf(amax, 1e-12f);
            float scale = amax / 6.0f;
            unsigned int pk[8];
            #pragma unroll
            for (int j = 0; j < 8; ++j) {
                unsigned short q2[2];
                #pragma unroll
                for (int e = 0; e < 2; ++e) {
                    float vv = v[2 * j + e];
                    float an = fabsf(vv) / scale;
                    float lev = 0.0f;
                    lev = an > 0.25f ? 0.5f : lev;
                    lev = an > 0.75f ? 1.0f : lev;
                    lev = an > 1.25f ? 1.5f : lev;
                    lev = an > 1.75f ? 2.0f : lev;
                    lev = an > 2.5f  ? 3.0f : lev;
                    lev = an > 3.5f  ? 4.0f : lev;
                    lev = an > 5.0f  ? 6.0f : lev;
                    q2[e] = f2bf(copysignf(lev * scale, vv));
                }
                pk[j] = (unsigned int)q2[0] | ((unsigned int)q2[1] << 16);
            }
            unsigned short* orow = xaug + (size_t)(row0 + rr) * KPAD + 16 * t;
            ((uint4*)orow)[0] = make_uint4(pk[0], pk[1], pk[2], pk[3]);
            ((uint4*)orow)[1] = make_uint4(pk[4], pk[5], pk[6], pk[7]);
        }
    }
    __syncthreads();

    // LoRA T: thread=(r=t>>3, c=t&7), rotated start for conflict-free LDS
    {
        const int r = t >> 3, c = t & 7;
        const float* ar = lora_a + (size_t)r * DIN;
        float acc4[ROWS_PB] = {0.f, 0.f, 0.f, 0.f};
        #pragma unroll 1
        for (int i = 0; i < 64; ++i) {
            const int d = (c << 9) + (((i << 3) + (c << 3)) & 511);
            float4 a0 = *(const float4*)(ar + d);
            float4 a1 = *(const float4*)(ar + d + 4);
            #pragma unroll
            for (int rr = 0; rr < ROWS_PB; ++rr) {
                uint4 xb = *(const uint4*)&xrot[rr][d];
                float x0 = __uint_as_float(xb.x << 16);
                float x1 = __uint_as_float(xb.x & 0xFFFF0000u);
                float x2 = __uint_as_float(xb.y << 16);
                float x3 = __uint_as_float(xb.y & 0xFFFF0000u);
                float x4 = __uint_as_float(xb.z << 16);
                float x5 = __uint_as_float(xb.z & 0xFFFF0000u);
                float x6 = __uint_as_float(xb.w << 16);
                float x7 = __uint_as_float(xb.w & 0xFFFF0000u);
                acc4[rr] += a0.x * x0 + a0.y * x1 + a0.z * x2 + a0.w * x3 +
                            a1.x * x4 + a1.y * x5 + a1.z * x6 + a1.w * x7;
            }
        }
        #pragma unroll
        for (int rr = 0; rr < ROWS_PB; ++rr) tred[rr][r][c] = acc4[rr];
    }
    __syncthreads();
    if (t < ROWS_PB * RANK) {
        const int rr = t >> 5, rk = t & 31;
        float s = 0.f;
        #pragma unroll
        for (int k = 0; k < 8; ++k) s += tred[rr][rk][k];
        xaug[(size_t)(row0 + rr) * KPAD + DIN + rk] = f2bf(s);
    }
}

// ---------------------------------------------------------------------------
// Kernel 2: 256x256 GEMM, kh-half-granular staging with 3-4 phase lead and
// counted vmcnt(4) (never 0 mid-loop). Per phase: {ds_read -> stage -> [vmcnt]
// -> barrier -> MFMA x16 -> barrier}. ds_read issued BEFORE the barrier so
// LDS latency hides under barrier-wait; raw s_barrier (no vmcnt-0 drain).
// LDS: As/Bs [2 dbuf][2 kh][16 KiB] = 128 KiB. Slot XOR s^(row&3) on 64 B
// rows spreads b128 reads over all 8 slot positions (conflict-free).
// ---------------------------------------------------------------------------
__global__ __launch_bounds__(512) void gemm_kernel(
    const unsigned short* __restrict__ A,   // [8192][4160] bf16 bits
    const unsigned short* __restrict__ Bm,  // [4096][4160] bf16 bits
    const float* __restrict__ bias,
    float* __restrict__ C)                  // [8192][4096]
{
    __shared__ unsigned short As[2][2][8192];   // [buf][kh][16 KiB]
    __shared__ unsigned short Bs[2][2][8192];

    const int bid = blockIdx.x;
    const int mt = bid >> 4, nt = bid & 15;      // 32 x 16 tiles
    const int m0 = mt * 256, n0 = nt * 256;
    const int t = threadIdx.x;
    const int wave = t >> 6, lane = t & 63;
    const int wm = wave >> 2, wn = wave & 3;     // wave tile 128x64
    const int lm = lane & 15, lq = lane >> 4;

    // staging lane constants: chunk = 16 rows x 32 cols (1 KiB), LDS linear.
    // lane l -> LDS row pr=l>>2, LDS slot l&3; global slot = (l&3)^(pr&3).
    const int pr = lane >> 2;
    const int sgs = (lane & 3) ^ (pr & 3);
    const int cc0 = wave * 2, cc1 = wave * 2 + 1;   // this wave's chunks

    // read-side byte offset within a kh-half (row lm, slot lq^(lm&3))
    const int rdo = lm * 64 + ((lq ^ (lm & 3)) << 4);

#define STG(MAT, RB, DST, KT, KH, CC) do {                                    \
    const unsigned short* g_ = (MAT) + (size_t)((RB) + (CC) * 16 + pr) * KPAD \
                               + (KT) * 64 + (KH) * 32 + sgs * 8;             \
    __builtin_amdgcn_global_load_lds(                                         \
        (const __attribute__((address_space(1))) void*)g_,                    \
        (__attribute__((address_space(3))) void*)((DST) + (CC) * 512),        \
        16, 0, 0); } while (0)

    floatx4 acc[8][4] = {};

    // prologue: stage tile 0 in consumption order, keep kh1 in flight
    STG(A,  m0, &As[0][0][0], 0, 0, cc0); STG(A,  m0, &As[0][0][0], 0, 0, cc1);
    STG(Bm, n0, &Bs[0][0][0], 0, 0, cc0); STG(Bm, n0, &Bs[0][0][0], 0, 0, cc1);
    STG(A,  m0, &As[0][1][0], 0, 1, cc0); STG(A,  m0, &As[0][1][0], 0, 1, cc1);
    STG(Bm, n0, &Bs[0][1][0], 0, 1, cc0); STG(Bm, n0, &Bs[0][1][0], 0, 1, cc1);
    asm volatile("s_waitcnt vmcnt(4)" ::: "memory");
    __builtin_amdgcn_s_barrier();

    #pragma unroll 1
    for (int kt = 0; kt < KTILES; ++kt) {
        const int b = kt & 1;
        const bool st = (kt + 1 < KTILES);
        const char* a0c = (const char*)&As[b][0][0];
        const char* a1c = (const char*)&As[b][1][0];
        const char* b0c = (const char*)&Bs[b][0][0];
        const char* b1c = (const char*)&Bs[b][1][0];
        unsigned short* nA0 = &As[b ^ 1][0][0];
        unsigned short* nA1 = &As[b ^ 1][1][0];
        unsigned short* nB0 = &Bs[b ^ 1][0][0];
        unsigned short* nB1 = &Bs[b ^ 1][1][0];
        short8 af[4], bf[4];

        // ---- P0: kh0, mi0-3 (+bf kh0); stage A-kh0 of kt+1
        #pragma unroll
        for (int i = 0; i < 4; ++i)
            af[i] = *(const short8*)(a0c + (wm * 8 + i) * 1024 + rdo);
        #pragma unroll
        for (int j = 0; j < 4; ++j)
            bf[j] = *(const short8*)(b0c + (wn * 4 + j) * 1024 + rdo);
        if (st) { STG(A, m0, nA0, kt + 1, 0, cc0); STG(A, m0, nA0, kt + 1, 0, cc1); }
        __builtin_amdgcn_sched_barrier(0);
        __builtin_amdgcn_s_barrier();
        __builtin_amdgcn_sched_barrier(0);
        __builtin_amdgcn_s_setprio(1);
        #pragma unroll
        for (int i = 0; i < 4; ++i)
            #pragma unroll
            for (int j = 0; j < 4; ++j)
                acc[i][j] = __builtin_amdgcn_mfma_f32_16x16x32_bf16(
                    af[i], bf[j], acc[i][j], 0, 0, 0);
        __builtin_amdgcn_s_setprio(0);
        __builtin_amdgcn_sched_barrier(0);
        __builtin_amdgcn_s_barrier();

        // ---- P1: kh0, mi4-7 (reuse bf); stage B-kh0; vmcnt(4)
        #pragma unroll
        for (int i = 0; i < 4; ++i)
            af[i] = *(const short8*)(a0c + (wm * 8 + 4 + i) * 1024 + rdo);
        if (st) {
            STG(Bm, n0, nB0, kt + 1, 0, cc0); STG(Bm, n0, nB0, kt + 1, 0, cc1);
            asm volatile("s_waitcnt vmcnt(4)" ::: "memory");
        } else {
            asm volatile("s_waitcnt vmcnt(0)" ::: "memory");
        }
        __builtin_amdgcn_sched_barrier(0);
        __builtin_amdgcn_s_barrier();
        __builtin_amdgcn_sched_barrier(0);
        __builtin_amdgcn_s_setprio(1);
        #pragma unroll
        for (int i = 0; i < 4; ++i)
            #pragma unroll
            for (int j = 0; j < 4; ++j)
                acc[i + 4][j] = __builtin_amdgcn_mfma_f32_16x16x32_bf16(
                    af[i], bf[j], acc[i + 4][j], 0, 0, 0);
        __builtin_amdgcn_s_setprio(0);
        __builtin_amdgcn_sched_barrier(0);
        __builtin_amdgcn_s_barrier();

        // ---- P2: kh1, mi0-3 (+bf kh1); stage A-kh1
        #pragma unroll
        for (int i = 0; i < 4; ++i)
            af[i] = *(const short8*)(a1c + (wm * 8 + i) * 1024 + rdo);
        #pragma unroll
        for (int j = 0; j < 4; ++j)
            bf[j] = *(const short8*)(b1c + (wn * 4 + j) * 1024 + rdo);
        if (st) { STG(A, m0, nA1, kt + 1, 1, cc0); STG(A, m0, nA1, kt + 1, 1, cc1); }
        __builtin_amdgcn_sched_barrier(0);
        __builtin_amdgcn_s_barrier();
        __builtin_amdgcn_sched_barrier(0);
        __builtin_amdgcn_s_setprio(1);
        #pragma unroll
        for (int i = 0; i < 4; ++i)
            #pragma unroll
            for (int j = 0; j < 4; ++j)
                acc[i][j] = __builtin_amdgcn_mfma_f32_16x16x32_bf16(
                    af[i], bf[j], acc[i][j], 0, 0, 0);
        __builtin_amdgcn_s_setprio(0);
        __builtin_amdgcn_sched_barrier(0);
        __builtin_amdgcn_s_barrier();

        // ---- P3: kh1, mi4-7; stage B-kh1; vmcnt(4)
        #pragma unroll
        for (int i = 0; i < 4; ++i)
            af[i] = *(const short8*)(a1c + (wm * 8 + 4 + i) * 1024 + rdo);
        if (st) {
            STG(Bm, n0, nB1, kt + 1, 1, cc0); STG(Bm, n0, nB1, kt + 1, 1, cc1);
            asm volatile("s_waitcnt vmcnt(4)" ::: "memory");
        }
        __builtin_amdgcn_sched_barrier(0);
        __builtin_amdgcn_s_barrier();
        __builtin_amdgcn_sched_barrier(0);
        __builtin_amdgcn_s_setprio(1);
        #pragma unroll
        for (int i = 0; i < 4; ++i)
            #pragma unroll
            for (int j = 0; j < 4; ++j)
                acc[i + 4][j] = __builtin_amdgcn_mfma_f32_16x16x32_bf16(
                    af[i], bf[j], acc[i + 4][j], 0, 0, 0);
        __builtin_amdgcn_s_setprio(0);
        __builtin_amdgcn_sched_barrier(0);
        __builtin_amdgcn_s_barrier();
    }
#undef STG

    // epilogue: += bias, store fp32
    float bv[4];
    #pragma unroll
    for (int j = 0; j < 4; ++j)
        bv[j] = bias[n0 + wn * 64 + j * 16 + lm];
    #pragma unroll
    for (int i = 0; i < 8; ++i) {
        #pragma unroll
        for (int j = 0; j < 4; ++j) {
            const int col = n0 + wn * 64 + j * 16 + lm;
            #pragma unroll
            for (int r = 0; r < 4; ++r) {
                const int row = m0 + wm * 128 + i * 16 + lq * 4 + r;
                C[(size_t)row * DOUT + col] = acc[i][j][r] + bv[j];
            }
        }
    }
}

// ---------------------------------------------------------------------------
extern "C" void kernel_launch(void* const* d_in, const int* in_sizes, int n_in,
                              void* d_out, int out_size, void* d_ws, size_t ws_size,
                              hipStream_t stream) {
    const float* x      = (const float*)d_in[0];
    const float* sgn    = (const float*)d_in[1];
    // d_in[2] = H_block (unused; Sylvester Hadamard via FWHT)
    const float* w      = (const float*)d_in[3];
    const float* lora_a = (const float*)d_in[4];
    const float* lora_b = (const float*)d_in[5];
    const float* bias   = (const float*)d_in[6];
    float* out = (float*)d_out;

    unsigned short* xaug = (unsigned short*)d_ws;                 // [8192][4160] bf16
    unsigned short* waug = xaug + (size_t)M_ROWS * KPAD;          // [4096][4160] bf16

    prep_kernel<<<NROTB + DOUT, 256, 0, stream>>>(x, sgn, lora_a, w, lora_b,
                                                  xaug, waug);
    gemm_kernel<<<(M_ROWS / 256) * (DOUT / 256), 512, 0, stream>>>(xaug, waug, bias, out);
}

// Round 5
// 650.142 us; speedup vs baseline: 1.2630x; 1.0003x over previous
//
#include <hip/hip_runtime.h>

#define M_ROWS 8192
#define DIN    4096
#define DOUT   4096
#define RANK   32
#define KAUG   4128   // DIN + RANK (valid data)
#define KPAD   4160   // 65*64: K padded to multiple of BK=64; pad zeroed
#define KTILES 65
#define ROWS_PB 4     // rows per block in rot_quant role
#define NROTB  (M_ROWS / ROWS_PB)   // 2048 rot blocks

typedef __attribute__((ext_vector_type(8))) short short8;
typedef __attribute__((ext_vector_type(4))) float floatx4;

__device__ __forceinline__ unsigned short f2bf(float f) {
    unsigned int u = __float_as_uint(f);
    unsigned int r = (u + 0x7FFFu + ((u >> 16) & 1u)) >> 16;  // RNE
    return (unsigned short)r;
}

// ---------------------------------------------------------------------------
// Kernel 1 (fused prep): blocks [0,2048) = rot_quant role (4 rows each),
// blocks [2048,6144) = cast_w role. Block-uniform branch.
// ---------------------------------------------------------------------------
__global__ __launch_bounds__(256) void prep_kernel(
    const float* __restrict__ x, const float* __restrict__ sgn,
    const float* __restrict__ lora_a,
    const float* __restrict__ w, const float* __restrict__ lora_b,
    unsigned short* __restrict__ xaug, unsigned short* __restrict__ waug)
{
    __shared__ unsigned short xrot[ROWS_PB][DIN];   // 32 KiB bf16 x_rot
    __shared__ float tred[ROWS_PB][RANK][8];        // 4 KiB partials

    const int t = threadIdx.x;

    if (blockIdx.x >= NROTB) {
        // ---- cast_w role ----
        const int n = blockIdx.x - NROTB;
        unsigned short* wr = waug + (size_t)n * KPAD;
        const float* wsrc = w + (size_t)n * DIN;
        #pragma unroll
        for (int it = 0; it < 2; ++it) {
            const int base = (it * 256 + t) * 8;
            float4 a = ((const float4*)wsrc)[base >> 2];
            float4 b = ((const float4*)wsrc)[(base >> 2) + 1];
            unsigned int p0 = (unsigned int)f2bf(a.x) | ((unsigned int)f2bf(a.y) << 16);
            unsigned int p1 = (unsigned int)f2bf(a.z) | ((unsigned int)f2bf(a.w) << 16);
            unsigned int p2 = (unsigned int)f2bf(b.x) | ((unsigned int)f2bf(b.y) << 16);
            unsigned int p3 = (unsigned int)f2bf(b.z) | ((unsigned int)f2bf(b.w) << 16);
            *(uint4*)(wr + base) = make_uint4(p0, p1, p2, p3);
        }
        if (t < RANK)
            wr[DIN + t] = f2bf(lora_b[(size_t)n * RANK + t]);
        if (t < 4)
            *(uint4*)&wr[KAUG + t * 8] = make_uint4(0, 0, 0, 0);
        return;
    }

    // ---- rot_quant role ----
    const int row0 = blockIdx.x * ROWS_PB;
    const float inv = 0.08838834764831845f;  // 1/sqrt(128)

    float sg[16];
    #pragma unroll
    for (int q = 0; q < 4; ++q)
        *(float4*)&sg[4 * q] = ((const float4*)sgn)[t * 4 + q];

    // zero the K padding [4128,4160)
    if (t < ROWS_PB * 4) {
        const int rr = t >> 2, q = t & 3;
        *(uint4*)&xaug[(size_t)(row0 + rr) * KPAD + KAUG + q * 8] =
            make_uint4(0, 0, 0, 0);
    }

    #pragma unroll 1
    for (int rr = 0; rr < ROWS_PB; ++rr) {
        const float* xr = x + (size_t)(row0 + rr) * DIN;
        float v[16];
        #pragma unroll
        for (int q = 0; q < 4; ++q)
            *(float4*)&v[4 * q] = ((const float4*)xr)[t * 4 + q];
        #pragma unroll
        for (int j = 0; j < 16; ++j) v[j] *= sg[j];

        // FWHT h=1,2,4,8 in-register
        #pragma unroll
        for (int h = 1; h < 16; h <<= 1) {
            #pragma unroll
            for (int i = 0; i < 16; ++i) {
                if (!(i & h)) {
                    float a = v[i], b = v[i + h];
                    v[i] = a + b;
                    v[i + h] = a - b;
                }
            }
        }
        // FWHT h=16,32,64 via shfl_xor in 8-lane groups
        #pragma unroll
        for (int m = 1; m <= 4; m <<= 1) {
            const bool up = (t & m) != 0;
            #pragma unroll
            for (int j = 0; j < 16; ++j) {
                float o = __shfl_xor(v[j], m, 64);
                v[j] = up ? (o - v[j]) : (v[j] + o);
            }
        }
        #pragma unroll
        for (int j = 0; j < 16; ++j) v[j] *= inv;

        // park x_rot bf16 in LDS
        {
            unsigned int xp[8];
            #pragma unroll
            for (int j = 0; j < 8; ++j)
                xp[j] = (unsigned int)f2bf(v[2 * j]) |
                        ((unsigned int)f2bf(v[2 * j + 1]) << 16);
            *(uint4*)&xrot[rr][16 * t]     = make_uint4(xp[0], xp[1], xp[2], xp[3]);
            *(uint4*)&xrot[rr][16 * t + 8] = make_uint4(xp[4], xp[5], xp[6], xp[7]);
        }

        // NVFP4 fake-quant -> bf16 Xaug
        {
            float amax = 0.f;
            #pragma unroll
            for (int j = 0; j < 16; ++j) amax = fmaxf(amax, fabsf(v[j]));
            amax = fmaxf(amax, 1e-12f);
            float scale = amax / 6.0f;
            unsigned int pk[8];
            #pragma unroll
            for (int j = 0; j < 8; ++j) {
                unsigned short q2[2];
                #pragma unroll
                for (int e = 0; e < 2; ++e) {
                    float vv = v[2 * j + e];
                    float an = fabsf(vv) / scale;
                    float lev = 0.0f;
                    lev = an > 0.25f ? 0.5f : lev;
                    lev = an > 0.75f ? 1.0f : lev;
                    lev = an > 1.25f ? 1.5f : lev;
                    lev = an > 1.75f ? 2.0f : lev;
                    lev = an > 2.5f  ? 3.0f : lev;
                    lev = an > 3.5f  ? 4.0f : lev;
                    lev = an > 5.0f  ? 6.0f : lev;
                    q2[e] = f2bf(copysignf(lev * scale, vv));
                }
                pk[j] = (unsigned int)q2[0] | ((unsigned int)q2[1] << 16);
            }
            unsigned short* orow = xaug + (size_t)(row0 + rr) * KPAD + 16 * t;
            ((uint4*)orow)[0] = make_uint4(pk[0], pk[1], pk[2], pk[3]);
            ((uint4*)orow)[1] = make_uint4(pk[4], pk[5], pk[6], pk[7]);
        }
    }
    __syncthreads();

    // LoRA T: thread=(r=t>>3, c=t&7), rotated start for conflict-free LDS
    {
        const int r = t >> 3, c = t & 7;
        const float* ar = lora_a + (size_t)r * DIN;
        float acc4[ROWS_PB] = {0.f, 0.f, 0.f, 0.f};
        #pragma unroll 1
        for (int i = 0; i < 64; ++i) {
            const int d = (c << 9) + (((i << 3) + (c << 3)) & 511);
            float4 a0 = *(const float4*)(ar + d);
            float4 a1 = *(const float4*)(ar + d + 4);
            #pragma unroll
            for (int rr = 0; rr < ROWS_PB; ++rr) {
                uint4 xb = *(const uint4*)&xrot[rr][d];
                float x0 = __uint_as_float(xb.x << 16);
                float x1 = __uint_as_float(xb.x & 0xFFFF0000u);
                float x2 = __uint_as_float(xb.y << 16);
                float x3 = __uint_as_float(xb.y & 0xFFFF0000u);
                float x4 = __uint_as_float(xb.z << 16);
                float x5 = __uint_as_float(xb.z & 0xFFFF0000u);
                float x6 = __uint_as_float(xb.w << 16);
                float x7 = __uint_as_float(xb.w & 0xFFFF0000u);
                acc4[rr] += a0.x * x0 + a0.y * x1 + a0.z * x2 + a0.w * x3 +
                            a1.x * x4 + a1.y * x5 + a1.z * x6 + a1.w * x7;
            }
        }
        #pragma unroll
        for (int rr = 0; rr < ROWS_PB; ++rr) tred[rr][r][c] = acc4[rr];
    }
    __syncthreads();
    if (t < ROWS_PB * RANK) {
        const int rr = t >> 5, rk = t & 31;
        float s = 0.f;
        #pragma unroll
        for (int k = 0; k < 8; ++k) s += tred[rr][rk][k];
        xaug[(size_t)(row0 + rr) * KPAD + DIN + rk] = f2bf(s);
    }
}

// ---------------------------------------------------------------------------
// Kernel 2: 256x256 GEMM, kh-half staging, counted vmcnt(4), phase interleave.
// Bank-conflict fix (r5): slot XOR period must differ from the slot field.
// Chunk rows are 64 B (bank base = (row&1)*16); slot XOR uses ((row>>1)&3)
// so within each 8-lane LDS cycle group the 8 lanes' 4-bank groups are the
// full bijection {0..7} -> 32 banks covered, conflict-free (r4 used (row&3):
// lanes lm and lm+4 collided -> 4-way, 2.56e7 conflicts, MfmaUtil capped 42%).
// ---------------------------------------------------------------------------
__global__ __launch_bounds__(512) void gemm_kernel(
    const unsigned short* __restrict__ A,   // [8192][4160] bf16 bits
    const unsigned short* __restrict__ Bm,  // [4096][4160] bf16 bits
    const float* __restrict__ bias,
    float* __restrict__ C)                  // [8192][4096]
{
    __shared__ unsigned short As[2][2][8192];   // [buf][kh][16 KiB]
    __shared__ unsigned short Bs[2][2][8192];

    const int bid = blockIdx.x;
    const int mt = bid >> 4, nt = bid & 15;      // 32 x 16 tiles
    const int m0 = mt * 256, n0 = nt * 256;
    const int t = threadIdx.x;
    const int wave = t >> 6, lane = t & 63;
    const int wm = wave >> 2, wn = wave & 3;     // wave tile 128x64
    const int lm = lane & 15, lq = lane >> 4;

    // staging: chunk = 16 rows x 32 cols (1 KiB), LDS linear.
    // lane l -> LDS row pr=l>>2, LDS slot l&3; GLOBAL slot = (l&3)^((pr>>1)&3).
    const int pr = lane >> 2;
    const int sgs = (lane & 3) ^ ((pr >> 1) & 3);
    const int cc0 = wave * 2, cc1 = wave * 2 + 1;   // this wave's chunks

    // read: row lm, LDS slot lq^((lm>>1)&3) -> global slot lq (k-offset lq*8)
    const int rdo = lm * 64 + ((lq ^ ((lm >> 1) & 3)) << 4);

#define STG(MAT, RB, DST, KT, KH, CC) do {                                    \
    const unsigned short* g_ = (MAT) + (size_t)((RB) + (CC) * 16 + pr) * KPAD \
                               + (KT) * 64 + (KH) * 32 + sgs * 8;             \
    __builtin_amdgcn_global_load_lds(                                         \
        (const __attribute__((address_space(1))) void*)g_,                    \
        (__attribute__((address_space(3))) void*)((DST) + (CC) * 512),        \
        16, 0, 0); } while (0)

    floatx4 acc[8][4] = {};

    // prologue: stage tile 0 in consumption order, keep kh1 in flight
    STG(A,  m0, &As[0][0][0], 0, 0, cc0); STG(A,  m0, &As[0][0][0], 0, 0, cc1);
    STG(Bm, n0, &Bs[0][0][0], 0, 0, cc0); STG(Bm, n0, &Bs[0][0][0], 0, 0, cc1);
    STG(A,  m0, &As[0][1][0], 0, 1, cc0); STG(A,  m0, &As[0][1][0], 0, 1, cc1);
    STG(Bm, n0, &Bs[0][1][0], 0, 1, cc0); STG(Bm, n0, &Bs[0][1][0], 0, 1, cc1);
    asm volatile("s_waitcnt vmcnt(4)" ::: "memory");
    __builtin_amdgcn_s_barrier();

    #pragma unroll 1
    for (int kt = 0; kt < KTILES; ++kt) {
        const int b = kt & 1;
        const bool st = (kt + 1 < KTILES);
        const char* a0c = (const char*)&As[b][0][0];
        const char* a1c = (const char*)&As[b][1][0];
        const char* b0c = (const char*)&Bs[b][0][0];
        const char* b1c = (const char*)&Bs[b][1][0];
        unsigned short* nA0 = &As[b ^ 1][0][0];
        unsigned short* nA1 = &As[b ^ 1][1][0];
        unsigned short* nB0 = &Bs[b ^ 1][0][0];
        unsigned short* nB1 = &Bs[b ^ 1][1][0];
        short8 af[4], bf[4];

        // ---- P0: kh0, mi0-3 (+bf kh0); stage A-kh0 of kt+1
        #pragma unroll
        for (int i = 0; i < 4; ++i)
            af[i] = *(const short8*)(a0c + (wm * 8 + i) * 1024 + rdo);
        #pragma unroll
        for (int j = 0; j < 4; ++j)
            bf[j] = *(const short8*)(b0c + (wn * 4 + j) * 1024 + rdo);
        if (st) { STG(A, m0, nA0, kt + 1, 0, cc0); STG(A, m0, nA0, kt + 1, 0, cc1); }
        __builtin_amdgcn_sched_barrier(0);
        __builtin_amdgcn_s_barrier();
        __builtin_amdgcn_sched_barrier(0);
        __builtin_amdgcn_s_setprio(1);
        #pragma unroll
        for (int i = 0; i < 4; ++i)
            #pragma unroll
            for (int j = 0; j < 4; ++j)
                acc[i][j] = __builtin_amdgcn_mfma_f32_16x16x32_bf16(
                    af[i], bf[j], acc[i][j], 0, 0, 0);
        __builtin_amdgcn_s_setprio(0);
        __builtin_amdgcn_sched_barrier(0);
        __builtin_amdgcn_s_barrier();

        // ---- P1: kh0, mi4-7 (reuse bf); stage B-kh0; vmcnt(4)
        #pragma unroll
        for (int i = 0; i < 4; ++i)
            af[i] = *(const short8*)(a0c + (wm * 8 + 4 + i) * 1024 + rdo);
        if (st) {
            STG(Bm, n0, nB0, kt + 1, 0, cc0); STG(Bm, n0, nB0, kt + 1, 0, cc1);
            asm volatile("s_waitcnt vmcnt(4)" ::: "memory");
        } else {
            asm volatile("s_waitcnt vmcnt(0)" ::: "memory");
        }
        __builtin_amdgcn_sched_barrier(0);
        __builtin_amdgcn_s_barrier();
        __builtin_amdgcn_sched_barrier(0);
        __builtin_amdgcn_s_setprio(1);
        #pragma unroll
        for (int i = 0; i < 4; ++i)
            #pragma unroll
            for (int j = 0; j < 4; ++j)
                acc[i + 4][j] = __builtin_amdgcn_mfma_f32_16x16x32_bf16(
                    af[i], bf[j], acc[i + 4][j], 0, 0, 0);
        __builtin_amdgcn_s_setprio(0);
        __builtin_amdgcn_sched_barrier(0);
        __builtin_amdgcn_s_barrier();

        // ---- P2: kh1, mi0-3 (+bf kh1); stage A-kh1
        #pragma unroll
        for (int i = 0; i < 4; ++i)
            af[i] = *(const short8*)(a1c + (wm * 8 + i) * 1024 + rdo);
        #pragma unroll
        for (int j = 0; j < 4; ++j)
            bf[j] = *(const short8*)(b1c + (wn * 4 + j) * 1024 + rdo);
        if (st) { STG(A, m0, nA1, kt + 1, 1, cc0); STG(A, m0, nA1, kt + 1, 1, cc1); }
        __builtin_amdgcn_sched_barrier(0);
        __builtin_amdgcn_s_barrier();
        __builtin_amdgcn_sched_barrier(0);
        __builtin_amdgcn_s_setprio(1);
        #pragma unroll
        for (int i = 0; i < 4; ++i)
            #pragma unroll
            for (int j = 0; j < 4; ++j)
                acc[i][j] = __builtin_amdgcn_mfma_f32_16x16x32_bf16(
                    af[i], bf[j], acc[i][j], 0, 0, 0);
        __builtin_amdgcn_s_setprio(0);
        __builtin_amdgcn_sched_barrier(0);
        __builtin_amdgcn_s_barrier();

        // ---- P3: kh1, mi4-7; stage B-kh1; vmcnt(4)
        #pragma unroll
        for (int i = 0; i < 4; ++i)
            af[i] = *(const short8*)(a1c + (wm * 8 + 4 + i) * 1024 + rdo);
        if (st) {
            STG(Bm, n0, nB1, kt + 1, 1, cc0); STG(Bm, n0, nB1, kt + 1, 1, cc1);
            asm volatile("s_waitcnt vmcnt(4)" ::: "memory");
        }
        __builtin_amdgcn_sched_barrier(0);
        __builtin_amdgcn_s_barrier();
        __builtin_amdgcn_sched_barrier(0);
        __builtin_amdgcn_s_setprio(1);
        #pragma unroll
        for (int i = 0; i < 4; ++i)
            #pragma unroll
            for (int j = 0; j < 4; ++j)
                acc[i + 4][j] = __builtin_amdgcn_mfma_f32_16x16x32_bf16(
                    af[i], bf[j], acc[i + 4][j], 0, 0, 0);
        __builtin_amdgcn_s_setprio(0);
        __builtin_amdgcn_sched_barrier(0);
        __builtin_amdgcn_s_barrier();
    }
#undef STG

    // epilogue: += bias, store fp32
    float bv[4];
    #pragma unroll
    for (int j = 0; j < 4; ++j)
        bv[j] = bias[n0 + wn * 64 + j * 16 + lm];
    #pragma unroll
    for (int i = 0; i < 8; ++i) {
        #pragma unroll
        for (int j = 0; j < 4; ++j) {
            const int col = n0 + wn * 64 + j * 16 + lm;
            #pragma unroll
            for (int r = 0; r < 4; ++r) {
                const int row = m0 + wm * 128 + i * 16 + lq * 4 + r;
                C[(size_t)row * DOUT + col] = acc[i][j][r] + bv[j];
            }
        }
    }
}

// ---------------------------------------------------------------------------
extern "C" void kernel_launch(void* const* d_in, const int* in_sizes, int n_in,
                              void* d_out, int out_size, void* d_ws, size_t ws_size,
                              hipStream_t stream) {
    const float* x      = (const float*)d_in[0];
    const float* sgn    = (const float*)d_in[1];
    // d_in[2] = H_block (unused; Sylvester Hadamard via FWHT)
    const float* w      = (const float*)d_in[3];
    const float* lora_a = (const float*)d_in[4];
    const float* lora_b = (const float*)d_in[5];
    const float* bias   = (const float*)d_in[6];
    float* out = (float*)d_out;

    unsigned short* xaug = (unsigned short*)d_ws;                 // [8192][4160] bf16
    unsigned short* waug = xaug + (size_t)M_ROWS * KPAD;          // [4096][4160] bf16

    prep_kernel<<<NROTB + DOUT, 256, 0, stream>>>(x, sgn, lora_a, w, lora_b,
                                                  xaug, waug);
    gemm_kernel<<<(M_ROWS / 256) * (DOUT / 256), 512, 0, stream>>>(xaug, waug, bias, out);
}